// Round 1
// baseline (226.738 us; speedup 1.0000x reference)
//
#include <hip/hip_runtime.h>
#include <hip/hip_bf16.h>
#include <math.h>

// Problem constants
#define N_  2
#define H_  8
#define G_  16      // N_*H_
#define L_  1024
#define S_  1024
#define E_  64
#define NC_ 6

typedef __attribute__((ext_vector_type(4))) float floatx4;
typedef __attribute__((ext_vector_type(8))) short short8;

#define MFMA16 __builtin_amdgcn_mfma_f32_16x16x32_bf16

// ---------------- workspace layout (bytes) ----------------
#define AHAT_OFF   0
#define AHAT_BYTES (NC_*G_*L_*128*2)          // 25,165,824
#define KHAT_OFF   (AHAT_OFF + AHAT_BYTES)
#define KHAT_BYTES (G_*S_*128*2)              //  4,194,304
#define PI_OFF     (KHAT_OFF + KHAT_BYTES)    // pi_t: [c][g][l] f32
#define PI_BYTES   (NC_*G_*L_*4)
#define HSQ_OFF    (PI_OFF + PI_BYTES)        // hsq: [c][g][l] f32
#define HSQ_BYTES  (NC_*G_*L_*4)
#define KSQ_OFF    (HSQ_OFF + HSQ_BYTES)      // ksq: [g][s] f32
#define KSQ_BYTES  (G_*S_*4)

// fast tanh: 1 - 2/(e^{2x}+1). Saturates correctly at +-inf; ~1e-7 rel err,
// far below the bf16 hi/lo split quantization downstream.
__device__ __forceinline__ float ftanh(float x) {
  return 1.0f - 2.0f * __builtin_amdgcn_rcpf(__expf(2.0f*x) + 1.0f);
}

// ---------------------------------------------------------------------------
// K1: htilde = tanh(q @ C[c,h]) -> bf16 hi/lo split + |htilde|^2.
// grid (8 l-chunks of 128, 6 codes, 16 g), 256 thr. One code per block:
// all 256 threads compute, reg-blocked 4 rows x 8 cols, vectorized LDS reads.
// LDS 52224 -> 3 blocks/CU (768 blocks = exactly resident).
// ---------------------------------------------------------------------------
__global__ __launch_bounds__(256) void k_htilde(
    const float* __restrict__ q, const float* __restrict__ C,
    __hip_bfloat16* __restrict__ Ahat, float* __restrict__ hsq) {
  extern __shared__ char smraw[];
  float* qs = (float*)smraw;             // [128][68]
  float* Cs = qs + 128*68;               // [64][68]

  const int lch = blockIdx.x, c = blockIdx.y, g = blockIdx.z;
  const int n = g >> 3, h = g & 7;
  const int l0 = lch * 128;
  const int t = threadIdx.x;

  for (int u = t; u < 2048; u += 256) {          // q: 128 rows x 16 segs
    int row = u >> 4, seg = u & 15;
    *(float4*)(qs + row*68 + seg*4) =
      *(const float4*)(q + (((size_t)(n*L_ + l0 + row))*H_ + h)*E_ + seg*4);
  }
  for (int u = t; u < 1024; u += 256) {          // C[c][h]: 64 rows x 16 segs
    int e = u >> 4, seg = u & 15;
    *(float4*)(Cs + e*68 + seg*4) =
      *(const float4*)(C + (((size_t)(c*8 + h))*64 + e)*64 + seg*4);
  }
  __syncthreads();

  const int rg = t >> 3, fg = t & 7;    // 32 row-groups x 4 rows; 8 col-octets
  float acc[4][8];
  #pragma unroll
  for (int i = 0; i < 4; i++)
    #pragma unroll
    for (int j = 0; j < 8; j++) acc[i][j] = 0.0f;

  #pragma unroll 4
  for (int e0 = 0; e0 < 64; e0 += 4) {
    float4 q4[4];
    #pragma unroll
    for (int i = 0; i < 4; i++)
      q4[i] = *(const float4*)(qs + (rg*4 + i)*68 + e0);
    #pragma unroll
    for (int ee = 0; ee < 4; ee++) {
      float4 ca = *(const float4*)(Cs + (e0+ee)*68 + fg*8);
      float4 cb = *(const float4*)(Cs + (e0+ee)*68 + fg*8 + 4);
      float c8[8] = {ca.x, ca.y, ca.z, ca.w, cb.x, cb.y, cb.z, cb.w};
      #pragma unroll
      for (int i = 0; i < 4; i++) {
        float qv = (ee == 0) ? q4[i].x : (ee == 1) ? q4[i].y
                 : (ee == 2) ? q4[i].z : q4[i].w;
        #pragma unroll
        for (int j = 0; j < 8; j++) acc[i][j] = fmaf(qv, c8[j], acc[i][j]);
      }
    }
  }

  #pragma unroll
  for (int i = 0; i < 4; i++) {
    int l = l0 + rg*4 + i;
    size_t rowb = (((size_t)(c*G_ + g))*L_ + l) * 128;
    float ss = 0.0f;
    short8 hi8, lo8;
    #pragma unroll
    for (int j = 0; j < 8; j++) {
      float hv = ftanh(acc[i][j]);
      ss += hv*hv;
      __hip_bfloat16 hi = __float2bfloat16(hv);
      __hip_bfloat16 lo = __float2bfloat16(hv - __bfloat162float(hi));
      short hs, ls;
      __builtin_memcpy(&hs, &hi, 2);
      __builtin_memcpy(&ls, &lo, 2);
      hi8[j] = hs; lo8[j] = ls;
    }
    *(short8*)((char*)Ahat + (rowb + fg*8)*2)      = hi8;
    *(short8*)((char*)Ahat + (rowb + 64 + fg*8)*2) = lo8;
    ss += __shfl_xor(ss, 1); ss += __shfl_xor(ss, 2); ss += __shfl_xor(ss, 4);
    if (fg == 0) hsq[((size_t)(c*G_ + g))*L_ + l] = ss;
  }
}

// ---------------------------------------------------------------------------
// K2: pi = softmax_k(q @ M[h]). grid 64 (16 g x 4 l-chunks of 256), 256 thr.
// ---------------------------------------------------------------------------
__global__ __launch_bounds__(256) void k_pi(
    const float* __restrict__ q, const float* __restrict__ M,
    float* __restrict__ pi_t) {
  __shared__ float Ms[384];
  const int g = blockIdx.x >> 2, lch = blockIdx.x & 3;
  const int n = g >> 3, h = g & 7;
  const int t = threadIdx.x;
  const int l = lch*256 + t;
  for (int u = t; u < 384; u += 256) Ms[u] = M[h*384 + u];  // M[h][e][k]
  __syncthreads();
  const float* qrow = q + (((size_t)(n*L_ + l))*H_ + h)*E_;
  float p[6] = {0.f, 0.f, 0.f, 0.f, 0.f, 0.f};
  #pragma unroll 8
  for (int e = 0; e < 64; e++) {
    float qv = qrow[e];
    #pragma unroll
    for (int k = 0; k < 6; k++) p[k] = fmaf(qv, Ms[e*6 + k], p[k]);
  }
  float mx = p[0];
  #pragma unroll
  for (int k = 1; k < 6; k++) mx = fmaxf(mx, p[k]);
  float den = 0.f;
  #pragma unroll
  for (int k = 0; k < 6; k++) den += __expf(p[k] - mx);
  float rden = __builtin_amdgcn_rcpf(den);
  #pragma unroll
  for (int k = 0; k < 6; k++)
    pi_t[((size_t)(k*G_ + g))*L_ + l] = __expf(p[k] - mx) * rden;
}

// ---------------------------------------------------------------------------
// K3: key split hi/lo + ksq. (R2-R7 proven)
// ---------------------------------------------------------------------------
__global__ __launch_bounds__(256) void k_key(
    const float* __restrict__ key, __hip_bfloat16* __restrict__ Khat,
    float* __restrict__ ksq) {
  int t = threadIdx.x; int wv = t >> 6; int lane = t & 63;
  int r = blockIdx.x*4 + wv;
  int g = r >> 10; int s = r & 1023; int n = g >> 3; int h = g & 7;
  float v = key[(((size_t)(n*S_ + s))*H_ + h)*E_ + lane];
  __hip_bfloat16 hi = __float2bfloat16(v);
  __hip_bfloat16 lo = __float2bfloat16(v - __bfloat162float(hi));
  size_t base = ((size_t)g*S_ + s)*128;
  Khat[base + lane]      = hi;
  Khat[base + 64 + lane] = lo;
  float sq = v*v;
  #pragma unroll
  for (int off = 32; off; off >>= 1) sq += __shfl_xor(sq, off);
  if (lane == 0) ksq[(size_t)g*S_ + s] = sq;
}

// ---------------------------------------------------------------------------
// K4: fused stats+emit, 2 sweeps — R10: NO LDS STAGING in the sweeps.
// Rationale: the old K_lds staging had ZERO intra-block reuse (each wave read
// a disjoint 16-row slice, every staged byte read from LDS exactly once), and
// cost 2 barriers/tile x 32 tiles with only 2 waves/SIMD resident (VGPR-capped
// occupancy: pool=256/slot, 3 waves needs <=85 VGPR -> spill). Khat slice per
// g is 256KB = L2-resident; read it (and a6f/hsq/ksq/klen) DIRECTLY from
// global. Only LDS left: 3.8KB cross-wave Z-reduction (2 barriers/kernel).
// Math unchanged: flat Z for L,O,R,W (bounded numerators; O via rcp); P flat
// with +64 shift (no overflow: 1024*e^64=6e30); online (m,z) for Y only.
// ---------------------------------------------------------------------------
#define LDS_ZRED  0                      // 4*96 f = 1536
#define LDS_MRED  1536                   // 4*96 f = 1536
#define LDS_CST   3072                   // 96 float2 = 768
#define LDS_TOTAL 3840

__global__ __launch_bounds__(256, 2) void k_main(
    const __hip_bfloat16* __restrict__ Ahat, const __hip_bfloat16* __restrict__ Khat,
    const float* __restrict__ hsq, const float* __restrict__ ksq,
    const float* __restrict__ mask, const float* __restrict__ klen,
    const float* __restrict__ pi_t, float* __restrict__ out) {
  extern __shared__ char smraw[];
  float*  zred   = (float*)(smraw + LDS_ZRED);
  float*  mred   = (float*)(smraw + LDS_MRED);
  float2* cst    = (float2*)(smraw + LDS_CST);

  const int l0 = blockIdx.x * 16; const int g = blockIdx.y; const int n = g >> 3;
  const int t = threadIdx.x; const int w = t >> 6; const int lane = t & 63;
  const int quad = lane >> 4; const int lc = lane & 15;

  // ---- A-fragments straight from global (L2/L3-resident, read once) ----
  // lane (quad,lc) owns Ahat row l0+lc, bytes kt*64 + quad*16 (same mapping
  // the old A6 staging produced).
  short8 a6f[6][4];
  #pragma unroll
  for (int cc = 0; cc < 6; cc++)
    #pragma unroll
    for (int kt = 0; kt < 4; kt++)
      a6f[cc][kt] = *(const short8*)((const char*)Ahat +
          (((size_t)(cc*G_ + g))*L_ + l0 + lc)*256 + kt*64 + quad*16);

  // per-(c,i) constants (scalar loads, 16-way broadcast across lc)
  float h1p[4], nh2[4], h4h[4], nh5[4];
  #pragma unroll
  for (int i = 0; i < 4; i++) {
    int r = quad*4 + i;
    h1p[i] = 1.0f + hsq[((size_t)(1*G_ + g))*L_ + l0 + r];
    nh2[i] = 64.0f - hsq[((size_t)(2*G_ + g))*L_ + l0 + r];   // P: +64 shift
    h4h[i] = -0.5f * hsq[((size_t)(4*G_ + g))*L_ + l0 + r];
    nh5[i] = -hsq[((size_t)(5*G_ + g))*L_ + l0 + r];
  }

  // Flat Z: Zc[0..3]={L,O,R,W}, zp=P(shifted). Online: (m3,z3)=Y.
  float Zc[4][4], zp[4], m3[4], z3[4];
  #pragma unroll
  for (int i = 0; i < 4; i++) {
    #pragma unroll
    for (int c = 0; c < 4; c++) Zc[c][i] = 0.0f;
    zp[i] = 0.0f; m3[i] = -INFINITY; z3[i] = 0.0f;
  }

  // ================= sweep 1: Z (no barriers, no LDS) =================
  #pragma unroll 1
  for (int st = 0; st < 16; st++) {
    int s0 = st*64;
    int scol = s0 + w*16 + lc;
    short8 bfr[4];
    #pragma unroll
    for (int kt = 0; kt < 4; kt++)
      bfr[kt] = *(const short8*)((const char*)Khat +
          (((size_t)g)*S_ + scol)*256 + kt*64 + quad*16);
    float kq  = ksq[(size_t)g*S_ + scol];
    float klv = klen[(size_t)n*S_ + scol];
    float mk[4];
    #pragma unroll
    for (int i = 0; i < 4; i++)
      mk[i] = mask[((size_t)(n*L_ + l0 + quad*4 + i))*S_ + scol];
    float mv[4], Ev[4], oc[4], pc[4], rc[4], wc[4];
    #pragma unroll
    for (int i = 0; i < 4; i++) {
      mv[i] = mk[i] + klv;
      Ev[i] = __expf(mv[i]);
      oc[i] = h1p[i] + kq;
      pc[i] = nh2[i] - kq + mv[i];
      rc[i] = fmaf(-0.5f, kq, h4h[i]);
      wc[i] = nh5[i] - kq;
    }
    #pragma unroll
    for (int c = 0; c < 6; c++) {
      floatx4 a = {0.f, 0.f, 0.f, 0.f};
      a = MFMA16(a6f[c][0], bfr[0], a, 0,0,0);
      a = MFMA16(a6f[c][1], bfr[1], a, 0,0,0);
      a = MFMA16(a6f[c][0], bfr[2], a, 0,0,0);
      a = MFMA16(a6f[c][1], bfr[3], a, 0,0,0);
      a = MFMA16(a6f[c][2], bfr[0], a, 0,0,0);
      a = MFMA16(a6f[c][3], bfr[1], a, 0,0,0);
      #pragma unroll
      for (int i = 0; i < 4; i++) {
        float d = a[i];
        if (c == 0) {
          Zc[0][i] = fmaf(Ev[i], __expf(d), Zc[0][i]);
        } else if (c == 1) {
          Zc[1][i] = fmaf(Ev[i], __builtin_amdgcn_rcpf(fmaf(-2.f, d, oc[i])), Zc[1][i]);
        } else if (c == 2) {                              // P flat, shifted
          zp[i] += __expf(fmaf(2.f, d, pc[i]));
        } else if (c == 3) {                              // Y online
          float tt = d + 1.f;
          float x  = fmaf(tt, tt, mv[i]);
          float mn = fmaxf(m3[i], x);
          float e  = __expf(fminf(m3[i], x) - mn);
          z3[i] = (x > m3[i]) ? fmaf(z3[i], e, 1.0f) : (z3[i] + e);
          m3[i] = mn;
        } else if (c == 4) {
          Zc[2][i] = fmaf(Ev[i], __expf(__expf(d + rc[i])), Zc[2][i]);
        } else {
          float a5 = fmaf(2.f, d, wc[i]);
          Zc[3][i] = fmaf(Ev[i], __expf(__cosf(a5) * __expf(a5)), Zc[3][i]);
        }
      }
    }
  }

  // ---- reduce across 16 lanes (butterfly) ----
  #pragma unroll
  for (int off = 1; off < 16; off <<= 1) {
    #pragma unroll
    for (int c = 0; c < 4; c++)
      #pragma unroll
      for (int i = 0; i < 4; i++) Zc[c][i] += __shfl_xor(Zc[c][i], off);
    #pragma unroll
    for (int i = 0; i < 4; i++) {
      zp[i] += __shfl_xor(zp[i], off);
      float mo = __shfl_xor(m3[i], off);
      float zo = __shfl_xor(z3[i], off);
      float mn = fmaxf(m3[i], mo);
      float e  = __expf(fminf(m3[i], mo) - mn);
      z3[i] = (mo > m3[i]) ? fmaf(z3[i], e, zo) : fmaf(zo, e, z3[i]);
      m3[i] = mn;
    }
  }
  if (lc == 0) {
    static const int cmap[4] = {0, 1, 4, 5};
    #pragma unroll
    for (int c = 0; c < 4; c++)
      #pragma unroll
      for (int i = 0; i < 4; i++) {
        zred[w*96 + cmap[c]*16 + quad*4 + i] = Zc[c][i];
        mred[w*96 + cmap[c]*16 + quad*4 + i] = 0.f;
      }
    #pragma unroll
    for (int i = 0; i < 4; i++) {
      zred[w*96 + 2*16 + quad*4 + i] = zp[i];
      mred[w*96 + 2*16 + quad*4 + i] = 0.f;
      zred[w*96 + 3*16 + quad*4 + i] = z3[i];
      mred[w*96 + 3*16 + quad*4 + i] = m3[i];
    }
  }
  __syncthreads();
  if (t < 96) {
    int c = t >> 4;
    float z = zred[t], m = mred[t];
    if (c == 3) {
      #pragma unroll
      for (int w2 = 1; w2 < 4; w2++) {
        float mo = mred[w2*96 + t], zo = zred[w2*96 + t];
        float mn = fmaxf(m, mo);
        float e  = __expf(fminf(m, mo) - mn);
        z = (mo > m) ? fmaf(z, e, zo) : fmaf(zo, e, z);
        m = mn;
      }
    } else {
      #pragma unroll
      for (int w2 = 1; w2 < 4; w2++) z += zred[w2*96 + t];
    }
    float piv = pi_t[((size_t)((t >> 4)*G_ + g))*L_ + l0 + (t & 15)];
    cst[t] = make_float2(piv / z, m);
  }
  __syncthreads();

  float ac[6][4], m3f[4];
  #pragma unroll
  for (int c = 0; c < 6; c++)
    #pragma unroll
    for (int i = 0; i < 4; i++) {
      float2 v = cst[c*16 + quad*4 + i];
      ac[c][i] = v.x;
      if (c == 3) m3f[i] = v.y;
    }

  // ================= sweep 2: emit (no barriers, no LDS) =================
  #pragma unroll 1
  for (int st = 0; st < 16; st++) {
    int s0 = st*64;
    int scol = s0 + w*16 + lc;
    short8 bfr[4];
    #pragma unroll
    for (int kt = 0; kt < 4; kt++)
      bfr[kt] = *(const short8*)((const char*)Khat +
          (((size_t)g)*S_ + scol)*256 + kt*64 + quad*16);
    float kq  = ksq[(size_t)g*S_ + scol];
    float klv = klen[(size_t)n*S_ + scol];
    float mk[4];
    #pragma unroll
    for (int i = 0; i < 4; i++)
      mk[i] = mask[((size_t)(n*L_ + l0 + quad*4 + i))*S_ + scol];
    float mv[4], Ev[4], oc[4], pc[4], rc[4], wc[4];
    #pragma unroll
    for (int i = 0; i < 4; i++) {
      mv[i] = mk[i] + klv;
      Ev[i] = __expf(mv[i]);
      oc[i] = h1p[i] + kq;
      pc[i] = nh2[i] - kq + mv[i];
      rc[i] = fmaf(-0.5f, kq, h4h[i]);
      wc[i] = nh5[i] - kq;
    }
    float Sacc[4] = {0.f, 0.f, 0.f, 0.f};   // Ev-scaled flat codes (L,O,R,W)
    float G[4]    = {0.f, 0.f, 0.f, 0.f};   // P (mv folded) + Y
    #pragma unroll
    for (int c = 0; c < 6; c++) {
      floatx4 a = {0.f, 0.f, 0.f, 0.f};
      a = MFMA16(a6f[c][0], bfr[0], a, 0,0,0);
      a = MFMA16(a6f[c][1], bfr[1], a, 0,0,0);
      a = MFMA16(a6f[c][0], bfr[2], a, 0,0,0);
      a = MFMA16(a6f[c][1], bfr[3], a, 0,0,0);
      a = MFMA16(a6f[c][2], bfr[0], a, 0,0,0);
      a = MFMA16(a6f[c][3], bfr[1], a, 0,0,0);
      #pragma unroll
      for (int i = 0; i < 4; i++) {
        float d = a[i];
        if (c == 0) {
          Sacc[i] = fmaf(ac[0][i], __expf(d), Sacc[i]);
        } else if (c == 1) {
          Sacc[i] = fmaf(ac[1][i], __builtin_amdgcn_rcpf(fmaf(-2.f, d, oc[i])), Sacc[i]);
        } else if (c == 2) {
          G[i] = fmaf(ac[2][i], __expf(fmaf(2.f, d, pc[i])), G[i]);
        } else if (c == 3) {
          float tt = d + 1.f;
          float x  = fmaf(tt, tt, mv[i]);
          G[i] = fmaf(ac[3][i], __expf(x - m3f[i]), G[i]);
        } else if (c == 4) {
          Sacc[i] = fmaf(ac[4][i], __expf(__expf(d + rc[i])), Sacc[i]);
        } else {
          float a5 = fmaf(2.f, d, wc[i]);
          Sacc[i] = fmaf(ac[5][i], __expf(__cosf(a5) * __expf(a5)), Sacc[i]);
        }
      }
    }
    #pragma unroll
    for (int i = 0; i < 4; i++)
      out[(((size_t)g)*L_ + l0 + quad*4 + i)*S_ + scol] = fmaf(Ev[i], Sacc[i], G[i]);
  }
}

// ---------------------------------------------------------------------------
extern "C" void kernel_launch(void* const* d_in, const int* in_sizes, int n_in,
                              void* d_out, int out_size, void* d_ws, size_t ws_size,
                              hipStream_t stream) {
  (void)in_sizes; (void)n_in; (void)out_size; (void)ws_size;
  const float* q    = (const float*)d_in[0];
  const float* key  = (const float*)d_in[1];
  const float* mask = (const float*)d_in[2];
  const float* klen = (const float*)d_in[3];
  const float* M    = (const float*)d_in[4];
  const float* C    = (const float*)d_in[5];
  char* ws = (char*)d_ws;
  __hip_bfloat16* Ahat = (__hip_bfloat16*)(ws + AHAT_OFF);
  __hip_bfloat16* Khat = (__hip_bfloat16*)(ws + KHAT_OFF);
  float* pi_t    = (float*)(ws + PI_OFF);
  float* hsq     = (float*)(ws + HSQ_OFF);
  float* ksq     = (float*)(ws + KSQ_OFF);
  float* out = (float*)d_out;

  k_htilde<<<dim3(8, 6, 16), 256, 52224, stream>>>(q, C, Ahat, hsq);
  k_key<<<4096, 256, 0, stream>>>(key, Khat, ksq);
  k_pi<<<64, 256, 0, stream>>>(q, M, pi_t);
  k_main<<<dim3(64, 16), 256, LDS_TOTAL, stream>>>(Ahat, Khat, hsq, ksq, mask, klen,
                                                   pi_t, out);
}

// Round 2
// 218.479 us; speedup vs baseline: 1.0378x; 1.0378x over previous
//
#include <hip/hip_runtime.h>
#include <hip/hip_bf16.h>
#include <math.h>

// Problem constants
#define N_  2
#define H_  8
#define G_  16      // N_*H_
#define L_  1024
#define S_  1024
#define E_  64
#define NC_ 6

typedef __attribute__((ext_vector_type(4))) float floatx4;
typedef __attribute__((ext_vector_type(8))) short short8;

#define MFMA16 __builtin_amdgcn_mfma_f32_16x16x32_bf16

// ---------------- workspace layout (bytes) ----------------
#define AHAT_OFF   0
#define AHAT_BYTES (NC_*G_*L_*128*2)          // 25,165,824
#define KHAT_OFF   (AHAT_OFF + AHAT_BYTES)
#define KHAT_BYTES (G_*S_*128*2)              //  4,194,304
#define PI_OFF     (KHAT_OFF + KHAT_BYTES)    // pi_t: [c][g][l] f32
#define PI_BYTES   (NC_*G_*L_*4)
#define HSQ_OFF    (PI_OFF + PI_BYTES)        // hsq: [c][g][l] f32
#define HSQ_BYTES  (NC_*G_*L_*4)
#define KSQ_OFF    (HSQ_OFF + HSQ_BYTES)      // ksq: [g][s] f32
#define KSQ_BYTES  (G_*S_*4)

// fast tanh: 1 - 2/(e^{2x}+1). Saturates correctly at +-inf; ~1e-7 rel err,
// far below the bf16 hi/lo split quantization downstream.
__device__ __forceinline__ float ftanh(float x) {
  return 1.0f - 2.0f * __builtin_amdgcn_rcpf(__expf(2.0f*x) + 1.0f);
}

// ---------------------------------------------------------------------------
// K1: htilde = tanh(q @ C[c,h]) -> bf16 hi/lo split + |htilde|^2. (unchanged)
// ---------------------------------------------------------------------------
__global__ __launch_bounds__(256) void k_htilde(
    const float* __restrict__ q, const float* __restrict__ C,
    __hip_bfloat16* __restrict__ Ahat, float* __restrict__ hsq) {
  extern __shared__ char smraw[];
  float* qs = (float*)smraw;             // [128][68]
  float* Cs = qs + 128*68;               // [64][68]

  const int lch = blockIdx.x, c = blockIdx.y, g = blockIdx.z;
  const int n = g >> 3, h = g & 7;
  const int l0 = lch * 128;
  const int t = threadIdx.x;

  for (int u = t; u < 2048; u += 256) {          // q: 128 rows x 16 segs
    int row = u >> 4, seg = u & 15;
    *(float4*)(qs + row*68 + seg*4) =
      *(const float4*)(q + (((size_t)(n*L_ + l0 + row))*H_ + h)*E_ + seg*4);
  }
  for (int u = t; u < 1024; u += 256) {          // C[c][h]: 64 rows x 16 segs
    int e = u >> 4, seg = u & 15;
    *(float4*)(Cs + e*68 + seg*4) =
      *(const float4*)(C + (((size_t)(c*8 + h))*64 + e)*64 + seg*4);
  }
  __syncthreads();

  const int rg = t >> 3, fg = t & 7;    // 32 row-groups x 4 rows; 8 col-octets
  float acc[4][8];
  #pragma unroll
  for (int i = 0; i < 4; i++)
    #pragma unroll
    for (int j = 0; j < 8; j++) acc[i][j] = 0.0f;

  #pragma unroll 4
  for (int e0 = 0; e0 < 64; e0 += 4) {
    float4 q4[4];
    #pragma unroll
    for (int i = 0; i < 4; i++)
      q4[i] = *(const float4*)(qs + (rg*4 + i)*68 + e0);
    #pragma unroll
    for (int ee = 0; ee < 4; ee++) {
      float4 ca = *(const float4*)(Cs + (e0+ee)*68 + fg*8);
      float4 cb = *(const float4*)(Cs + (e0+ee)*68 + fg*8 + 4);
      float c8[8] = {ca.x, ca.y, ca.z, ca.w, cb.x, cb.y, cb.z, cb.w};
      #pragma unroll
      for (int i = 0; i < 4; i++) {
        float qv = (ee == 0) ? q4[i].x : (ee == 1) ? q4[i].y
                 : (ee == 2) ? q4[i].z : q4[i].w;
        #pragma unroll
        for (int j = 0; j < 8; j++) acc[i][j] = fmaf(qv, c8[j], acc[i][j]);
      }
    }
  }

  #pragma unroll
  for (int i = 0; i < 4; i++) {
    int l = l0 + rg*4 + i;
    size_t rowb = (((size_t)(c*G_ + g))*L_ + l) * 128;
    float ss = 0.0f;
    short8 hi8, lo8;
    #pragma unroll
    for (int j = 0; j < 8; j++) {
      float hv = ftanh(acc[i][j]);
      ss += hv*hv;
      __hip_bfloat16 hi = __float2bfloat16(hv);
      __hip_bfloat16 lo = __float2bfloat16(hv - __bfloat162float(hi));
      short hs, ls;
      __builtin_memcpy(&hs, &hi, 2);
      __builtin_memcpy(&ls, &lo, 2);
      hi8[j] = hs; lo8[j] = ls;
    }
    *(short8*)((char*)Ahat + (rowb + fg*8)*2)      = hi8;
    *(short8*)((char*)Ahat + (rowb + 64 + fg*8)*2) = lo8;
    ss += __shfl_xor(ss, 1); ss += __shfl_xor(ss, 2); ss += __shfl_xor(ss, 4);
    if (fg == 0) hsq[((size_t)(c*G_ + g))*L_ + l] = ss;
  }
}

// ---------------------------------------------------------------------------
// K2: pi = softmax_k(q @ M[h]). (unchanged)
// ---------------------------------------------------------------------------
__global__ __launch_bounds__(256) void k_pi(
    const float* __restrict__ q, const float* __restrict__ M,
    float* __restrict__ pi_t) {
  __shared__ float Ms[384];
  const int g = blockIdx.x >> 2, lch = blockIdx.x & 3;
  const int n = g >> 3, h = g & 7;
  const int t = threadIdx.x;
  const int l = lch*256 + t;
  for (int u = t; u < 384; u += 256) Ms[u] = M[h*384 + u];  // M[h][e][k]
  __syncthreads();
  const float* qrow = q + (((size_t)(n*L_ + l))*H_ + h)*E_;
  float p[6] = {0.f, 0.f, 0.f, 0.f, 0.f, 0.f};
  #pragma unroll 8
  for (int e = 0; e < 64; e++) {
    float qv = qrow[e];
    #pragma unroll
    for (int k = 0; k < 6; k++) p[k] = fmaf(qv, Ms[e*6 + k], p[k]);
  }
  float mx = p[0];
  #pragma unroll
  for (int k = 1; k < 6; k++) mx = fmaxf(mx, p[k]);
  float den = 0.f;
  #pragma unroll
  for (int k = 0; k < 6; k++) den += __expf(p[k] - mx);
  float rden = __builtin_amdgcn_rcpf(den);
  #pragma unroll
  for (int k = 0; k < 6; k++)
    pi_t[((size_t)(k*G_ + g))*L_ + l] = __expf(p[k] - mx) * rden;
}

// ---------------------------------------------------------------------------
// K3: key split hi/lo + ksq. (unchanged)
// ---------------------------------------------------------------------------
__global__ __launch_bounds__(256) void k_key(
    const float* __restrict__ key, __hip_bfloat16* __restrict__ Khat,
    float* __restrict__ ksq) {
  int t = threadIdx.x; int wv = t >> 6; int lane = t & 63;
  int r = blockIdx.x*4 + wv;
  int g = r >> 10; int s = r & 1023; int n = g >> 3; int h = g & 7;
  float v = key[(((size_t)(n*S_ + s))*H_ + h)*E_ + lane];
  __hip_bfloat16 hi = __float2bfloat16(v);
  __hip_bfloat16 lo = __float2bfloat16(v - __bfloat162float(hi));
  size_t base = ((size_t)g*S_ + s)*128;
  Khat[base + lane]      = hi;
  Khat[base + 64 + lane] = lo;
  float sq = v*v;
  #pragma unroll
  for (int off = 32; off; off >>= 1) sq += __shfl_xor(sq, off);
  if (lane == 0) ksq[(size_t)g*S_ + s] = sq;
}

// ---------------------------------------------------------------------------
// K4: fused stats+emit, 2 sweeps — R11.
// R10 lesson: barriers weren't the cost; latency stall at 2 waves/SIMD was.
// Occupancy was register-limited: a6f[6][4] = 96 regs of payload IDENTICAL
// across all 4 waves pushed unified VGPR+AGPR past the 128 step (VGPR_Count
// 108 is arch-only). Fix:
//  * A-fragments live in LDS (staged once, stride 272 — the proven R7
//    conflict-light pattern), re-read 4x ds_read_b128 per code per tile.
//    Frees ~80 unified regs -> 4 waves/SIMD.
//  * K-fragments: 2-deep register prefetch (next tile's 4x16B global loads
//    issue before current tile's compute). Scalars (ksq/klen/mask) load
//    in-tile: first use is after the MFMA cluster, latency covered.
//  * oc/pc/rc/wc inlined at single use site (same math, -16 live regs).
// No barriers in the sweeps (only the initial stage + 2 reduction barriers).
// Math unchanged: flat Z for L,O,R,W; P flat +64 shift; online (m,z) for Y.
// ---------------------------------------------------------------------------
#define LDS_A6    0                      // 96 rows * 272 B = 26112
#define LDS_ZRED  26112                  // 4*96 f = 1536
#define LDS_MRED  27648                  // 4*96 f = 1536
#define LDS_CST   29184                  // 96 float2 = 768
#define LDS_TOTAL 29952

__global__ __launch_bounds__(256, 2) void k_main(
    const __hip_bfloat16* __restrict__ Ahat, const __hip_bfloat16* __restrict__ Khat,
    const float* __restrict__ hsq, const float* __restrict__ ksq,
    const float* __restrict__ mask, const float* __restrict__ klen,
    const float* __restrict__ pi_t, float* __restrict__ out) {
  extern __shared__ char smraw[];
  char*   A6     = smraw + LDS_A6;
  float*  zred   = (float*)(smraw + LDS_ZRED);
  float*  mred   = (float*)(smraw + LDS_MRED);
  float2* cst    = (float2*)(smraw + LDS_CST);

  const int l0 = blockIdx.x * 16; const int g = blockIdx.y; const int n = g >> 3;
  const int t = threadIdx.x; const int w = t >> 6; const int lane = t & 63;
  const int quad = lane >> 4; const int lc = lane & 15;

  // ---- stage A6 once: 6 codes x 16 rows x 256B, stride 272 ----
  #pragma unroll
  for (int rep = 0; rep < 6; rep++) {
    int u = t + rep*256; int row = u >> 4, seg = u & 15;   // row 0..95
    int cc = row >> 4, lr = row & 15;
    *(int4*)(A6 + row*272 + seg*16) =
      *(const int4*)((const char*)Ahat + (((size_t)(cc*G_ + g))*L_ + l0 + lr)*256 + seg*16);
  }
  __syncthreads();

  // per-(c,i) constants (scalar loads, broadcast across lc)
  float h1p[4], nh2[4], h4h[4], nh5[4];
  #pragma unroll
  for (int i = 0; i < 4; i++) {
    int r = quad*4 + i;
    h1p[i] = 1.0f + hsq[((size_t)(1*G_ + g))*L_ + l0 + r];
    nh2[i] = 64.0f - hsq[((size_t)(2*G_ + g))*L_ + l0 + r];   // P: +64 shift
    h4h[i] = -0.5f * hsq[((size_t)(4*G_ + g))*L_ + l0 + r];
    nh5[i] = -hsq[((size_t)(5*G_ + g))*L_ + l0 + r];
  }

  // K-fragment loader (4 x 16B from global; L2-resident)
  auto LOADB = [&](int st, short8 (&bf)[4]) {
    const char* base = (const char*)Khat +
        (((size_t)g)*S_ + st*64 + w*16 + lc)*256 + quad*16;
    #pragma unroll
    for (int kt = 0; kt < 4; kt++)
      bf[kt] = *(const short8*)(base + kt*64);
  };

  // Flat Z: Zc[0..3]={L,O,R,W}, zp=P(shifted). Online: (m3,z3)=Y.
  float Zc[4][4], zp[4], m3[4], z3[4];
  #pragma unroll
  for (int i = 0; i < 4; i++) {
    #pragma unroll
    for (int c = 0; c < 4; c++) Zc[c][i] = 0.0f;
    zp[i] = 0.0f; m3[i] = -INFINITY; z3[i] = 0.0f;
  }

  // ================= sweep 1: Z =================
  auto SWEEP1 = [&](int st, const short8 (&bf)[4]) {
    int scol = st*64 + w*16 + lc;
    float kq  = ksq[(size_t)g*S_ + scol];
    float klv = klen[(size_t)n*S_ + scol];
    float mv[4], Ev[4];
    #pragma unroll
    for (int i = 0; i < 4; i++) {
      mv[i] = mask[((size_t)(n*L_ + l0 + quad*4 + i))*S_ + scol] + klv;
      Ev[i] = __expf(mv[i]);
    }
    #pragma unroll
    for (int c = 0; c < 6; c++) {
      short8 af[4];
      #pragma unroll
      for (int kt = 0; kt < 4; kt++)
        af[kt] = *(const short8*)(A6 + (c*16 + lc)*272 + kt*64 + quad*16);
      floatx4 a = {0.f, 0.f, 0.f, 0.f};
      a = MFMA16(af[0], bf[0], a, 0,0,0);
      a = MFMA16(af[1], bf[1], a, 0,0,0);
      a = MFMA16(af[0], bf[2], a, 0,0,0);
      a = MFMA16(af[1], bf[3], a, 0,0,0);
      a = MFMA16(af[2], bf[0], a, 0,0,0);
      a = MFMA16(af[3], bf[1], a, 0,0,0);
      #pragma unroll
      for (int i = 0; i < 4; i++) {
        float d = a[i];
        if (c == 0) {
          Zc[0][i] = fmaf(Ev[i], __expf(d), Zc[0][i]);
        } else if (c == 1) {
          Zc[1][i] = fmaf(Ev[i],
              __builtin_amdgcn_rcpf(fmaf(-2.f, d, h1p[i] + kq)), Zc[1][i]);
        } else if (c == 2) {                              // P flat, shifted
          zp[i] += __expf(fmaf(2.f, d, nh2[i] - kq + mv[i]));
        } else if (c == 3) {                              // Y online
          float tt = d + 1.f;
          float x  = fmaf(tt, tt, mv[i]);
          float mn = fmaxf(m3[i], x);
          float e  = __expf(fminf(m3[i], x) - mn);
          z3[i] = (x > m3[i]) ? fmaf(z3[i], e, 1.0f) : (z3[i] + e);
          m3[i] = mn;
        } else if (c == 4) {
          Zc[2][i] = fmaf(Ev[i],
              __expf(__expf(d + fmaf(-0.5f, kq, h4h[i]))), Zc[2][i]);
        } else {
          float a5 = fmaf(2.f, d, nh5[i] - kq);
          Zc[3][i] = fmaf(Ev[i], __expf(__cosf(a5) * __expf(a5)), Zc[3][i]);
        }
      }
    }
  };

  {
    short8 bA[4], bB[4];
    LOADB(0, bA);
    #pragma unroll 1
    for (int st = 0; st < 16; st += 2) {
      LOADB(st + 1, bB);
      SWEEP1(st, bA);
      LOADB((st + 2) & 15, bA);
      SWEEP1(st + 1, bB);
    }
  }

  // ---- reduce across 16 lanes (butterfly) ----
  #pragma unroll
  for (int off = 1; off < 16; off <<= 1) {
    #pragma unroll
    for (int c = 0; c < 4; c++)
      #pragma unroll
      for (int i = 0; i < 4; i++) Zc[c][i] += __shfl_xor(Zc[c][i], off);
    #pragma unroll
    for (int i = 0; i < 4; i++) {
      zp[i] += __shfl_xor(zp[i], off);
      float mo = __shfl_xor(m3[i], off);
      float zo = __shfl_xor(z3[i], off);
      float mn = fmaxf(m3[i], mo);
      float e  = __expf(fminf(m3[i], mo) - mn);
      z3[i] = (mo > m3[i]) ? fmaf(z3[i], e, zo) : fmaf(zo, e, z3[i]);
      m3[i] = mn;
    }
  }
  if (lc == 0) {
    static const int cmap[4] = {0, 1, 4, 5};
    #pragma unroll
    for (int c = 0; c < 4; c++)
      #pragma unroll
      for (int i = 0; i < 4; i++) {
        zred[w*96 + cmap[c]*16 + quad*4 + i] = Zc[c][i];
        mred[w*96 + cmap[c]*16 + quad*4 + i] = 0.f;
      }
    #pragma unroll
    for (int i = 0; i < 4; i++) {
      zred[w*96 + 2*16 + quad*4 + i] = zp[i];
      mred[w*96 + 2*16 + quad*4 + i] = 0.f;
      zred[w*96 + 3*16 + quad*4 + i] = z3[i];
      mred[w*96 + 3*16 + quad*4 + i] = m3[i];
    }
  }
  __syncthreads();
  if (t < 96) {
    int c = t >> 4;
    float z = zred[t], m = mred[t];
    if (c == 3) {
      #pragma unroll
      for (int w2 = 1; w2 < 4; w2++) {
        float mo = mred[w2*96 + t], zo = zred[w2*96 + t];
        float mn = fmaxf(m, mo);
        float e  = __expf(fminf(m, mo) - mn);
        z = (mo > m) ? fmaf(z, e, zo) : fmaf(zo, e, z);
        m = mn;
      }
    } else {
      #pragma unroll
      for (int w2 = 1; w2 < 4; w2++) z += zred[w2*96 + t];
    }
    float piv = pi_t[((size_t)((t >> 4)*G_ + g))*L_ + l0 + (t & 15)];
    cst[t] = make_float2(piv / z, m);
  }
  __syncthreads();

  float ac[6][4], m3f[4];
  #pragma unroll
  for (int c = 0; c < 6; c++)
    #pragma unroll
    for (int i = 0; i < 4; i++) {
      float2 v = cst[c*16 + quad*4 + i];
      ac[c][i] = v.x;
      if (c == 3) m3f[i] = v.y;
    }

  // ================= sweep 2: emit =================
  auto SWEEP2 = [&](int st, const short8 (&bf)[4]) {
    int scol = st*64 + w*16 + lc;
    float kq  = ksq[(size_t)g*S_ + scol];
    float klv = klen[(size_t)n*S_ + scol];
    float mv[4], Ev[4];
    #pragma unroll
    for (int i = 0; i < 4; i++) {
      mv[i] = mask[((size_t)(n*L_ + l0 + quad*4 + i))*S_ + scol] + klv;
      Ev[i] = __expf(mv[i]);
    }
    float Sacc[4] = {0.f, 0.f, 0.f, 0.f};   // Ev-scaled flat codes (L,O,R,W)
    float Gg[4]   = {0.f, 0.f, 0.f, 0.f};   // P (mv folded) + Y
    #pragma unroll
    for (int c = 0; c < 6; c++) {
      short8 af[4];
      #pragma unroll
      for (int kt = 0; kt < 4; kt++)
        af[kt] = *(const short8*)(A6 + (c*16 + lc)*272 + kt*64 + quad*16);
      floatx4 a = {0.f, 0.f, 0.f, 0.f};
      a = MFMA16(af[0], bf[0], a, 0,0,0);
      a = MFMA16(af[1], bf[1], a, 0,0,0);
      a = MFMA16(af[0], bf[2], a, 0,0,0);
      a = MFMA16(af[1], bf[3], a, 0,0,0);
      a = MFMA16(af[2], bf[0], a, 0,0,0);
      a = MFMA16(af[3], bf[1], a, 0,0,0);
      #pragma unroll
      for (int i = 0; i < 4; i++) {
        float d = a[i];
        if (c == 0) {
          Sacc[i] = fmaf(ac[0][i], __expf(d), Sacc[i]);
        } else if (c == 1) {
          Sacc[i] = fmaf(ac[1][i],
              __builtin_amdgcn_rcpf(fmaf(-2.f, d, h1p[i] + kq)), Sacc[i]);
        } else if (c == 2) {
          Gg[i] = fmaf(ac[2][i], __expf(fmaf(2.f, d, nh2[i] - kq + mv[i])), Gg[i]);
        } else if (c == 3) {
          float tt = d + 1.f;
          float x  = fmaf(tt, tt, mv[i]);
          Gg[i] = fmaf(ac[3][i], __expf(x - m3f[i]), Gg[i]);
        } else if (c == 4) {
          Sacc[i] = fmaf(ac[4][i],
              __expf(__expf(d + fmaf(-0.5f, kq, h4h[i]))), Sacc[i]);
        } else {
          float a5 = fmaf(2.f, d, nh5[i] - kq);
          Sacc[i] = fmaf(ac[5][i], __expf(__cosf(a5) * __expf(a5)), Sacc[i]);
        }
      }
    }
    #pragma unroll
    for (int i = 0; i < 4; i++)
      out[(((size_t)g)*L_ + l0 + quad*4 + i)*S_ + scol] = fmaf(Ev[i], Sacc[i], Gg[i]);
  };

  {
    short8 bA[4], bB[4];
    LOADB(0, bA);
    #pragma unroll 1
    for (int st = 0; st < 16; st += 2) {
      LOADB(st + 1, bB);
      SWEEP2(st, bA);
      LOADB((st + 2) & 15, bA);
      SWEEP2(st + 1, bB);
    }
  }
}

// ---------------------------------------------------------------------------
extern "C" void kernel_launch(void* const* d_in, const int* in_sizes, int n_in,
                              void* d_out, int out_size, void* d_ws, size_t ws_size,
                              hipStream_t stream) {
  (void)in_sizes; (void)n_in; (void)out_size; (void)ws_size;
  const float* q    = (const float*)d_in[0];
  const float* key  = (const float*)d_in[1];
  const float* mask = (const float*)d_in[2];
  const float* klen = (const float*)d_in[3];
  const float* M    = (const float*)d_in[4];
  const float* C    = (const float*)d_in[5];
  char* ws = (char*)d_ws;
  __hip_bfloat16* Ahat = (__hip_bfloat16*)(ws + AHAT_OFF);
  __hip_bfloat16* Khat = (__hip_bfloat16*)(ws + KHAT_OFF);
  float* pi_t    = (float*)(ws + PI_OFF);
  float* hsq     = (float*)(ws + HSQ_OFF);
  float* ksq     = (float*)(ws + KSQ_OFF);
  float* out = (float*)d_out;

  k_htilde<<<dim3(8, 6, 16), 256, 52224, stream>>>(q, C, Ahat, hsq);
  k_key<<<4096, 256, 0, stream>>>(key, Khat, ksq);
  k_pi<<<64, 256, 0, stream>>>(q, M, pi_t);
  k_main<<<dim3(64, 16), 256, LDS_TOTAL, stream>>>(Ahat, Khat, hsq, ksq, mask, klen,
                                                   pi_t, out);
}

// Round 3
// 202.651 us; speedup vs baseline: 1.1189x; 1.0781x over previous
//
#include <hip/hip_runtime.h>
#include <hip/hip_bf16.h>
#include <math.h>

// Problem constants
#define N_  2
#define H_  8
#define G_  16      // N_*H_
#define L_  1024
#define S_  1024
#define E_  64
#define NC_ 6

typedef __attribute__((ext_vector_type(4))) float floatx4;
typedef __attribute__((ext_vector_type(8))) short short8;

#define MFMA16 __builtin_amdgcn_mfma_f32_16x16x32_bf16

// ---------------- workspace layout (bytes) ----------------
#define AHAT_OFF   0
#define AHAT_BYTES (NC_*G_*L_*128*2)          // 25,165,824
#define KHAT_OFF   (AHAT_OFF + AHAT_BYTES)
#define KHAT_BYTES (G_*S_*128*2)              //  4,194,304
#define PI_OFF     (KHAT_OFF + KHAT_BYTES)    // pi_t: [c][g][l] f32
#define PI_BYTES   (NC_*G_*L_*4)
#define HSQ_OFF    (PI_OFF + PI_BYTES)        // hsq: [c][g][l] f32
#define HSQ_BYTES  (NC_*G_*L_*4)
#define KSQ_OFF    (HSQ_OFF + HSQ_BYTES)      // ksq: [g][s] f32
#define KSQ_BYTES  (G_*S_*4)

// fast tanh: 1 - 2/(e^{2x}+1). Saturates correctly at +-inf; ~1e-7 rel err,
// far below the bf16 hi/lo split quantization downstream.
__device__ __forceinline__ float ftanh(float x) {
  return 1.0f - 2.0f * __builtin_amdgcn_rcpf(__expf(2.0f*x) + 1.0f);
}

// ---------------------------------------------------------------------------
// K1: htilde = tanh(q @ C[c,h]) -> bf16 hi/lo split + |htilde|^2. (unchanged)
// ---------------------------------------------------------------------------
__global__ __launch_bounds__(256) void k_htilde(
    const float* __restrict__ q, const float* __restrict__ C,
    __hip_bfloat16* __restrict__ Ahat, float* __restrict__ hsq) {
  extern __shared__ char smraw[];
  float* qs = (float*)smraw;             // [128][68]
  float* Cs = qs + 128*68;               // [64][68]

  const int lch = blockIdx.x, c = blockIdx.y, g = blockIdx.z;
  const int n = g >> 3, h = g & 7;
  const int l0 = lch * 128;
  const int t = threadIdx.x;

  for (int u = t; u < 2048; u += 256) {          // q: 128 rows x 16 segs
    int row = u >> 4, seg = u & 15;
    *(float4*)(qs + row*68 + seg*4) =
      *(const float4*)(q + (((size_t)(n*L_ + l0 + row))*H_ + h)*E_ + seg*4);
  }
  for (int u = t; u < 1024; u += 256) {          // C[c][h]: 64 rows x 16 segs
    int e = u >> 4, seg = u & 15;
    *(float4*)(Cs + e*68 + seg*4) =
      *(const float4*)(C + (((size_t)(c*8 + h))*64 + e)*64 + seg*4);
  }
  __syncthreads();

  const int rg = t >> 3, fg = t & 7;    // 32 row-groups x 4 rows; 8 col-octets
  float acc[4][8];
  #pragma unroll
  for (int i = 0; i < 4; i++)
    #pragma unroll
    for (int j = 0; j < 8; j++) acc[i][j] = 0.0f;

  #pragma unroll 4
  for (int e0 = 0; e0 < 64; e0 += 4) {
    float4 q4[4];
    #pragma unroll
    for (int i = 0; i < 4; i++)
      q4[i] = *(const float4*)(qs + (rg*4 + i)*68 + e0);
    #pragma unroll
    for (int ee = 0; ee < 4; ee++) {
      float4 ca = *(const float4*)(Cs + (e0+ee)*68 + fg*8);
      float4 cb = *(const float4*)(Cs + (e0+ee)*68 + fg*8 + 4);
      float c8[8] = {ca.x, ca.y, ca.z, ca.w, cb.x, cb.y, cb.z, cb.w};
      #pragma unroll
      for (int i = 0; i < 4; i++) {
        float qv = (ee == 0) ? q4[i].x : (ee == 1) ? q4[i].y
                 : (ee == 2) ? q4[i].z : q4[i].w;
        #pragma unroll
        for (int j = 0; j < 8; j++) acc[i][j] = fmaf(qv, c8[j], acc[i][j]);
      }
    }
  }

  #pragma unroll
  for (int i = 0; i < 4; i++) {
    int l = l0 + rg*4 + i;
    size_t rowb = (((size_t)(c*G_ + g))*L_ + l) * 128;
    float ss = 0.0f;
    short8 hi8, lo8;
    #pragma unroll
    for (int j = 0; j < 8; j++) {
      float hv = ftanh(acc[i][j]);
      ss += hv*hv;
      __hip_bfloat16 hi = __float2bfloat16(hv);
      __hip_bfloat16 lo = __float2bfloat16(hv - __bfloat162float(hi));
      short hs, ls;
      __builtin_memcpy(&hs, &hi, 2);
      __builtin_memcpy(&ls, &lo, 2);
      hi8[j] = hs; lo8[j] = ls;
    }
    *(short8*)((char*)Ahat + (rowb + fg*8)*2)      = hi8;
    *(short8*)((char*)Ahat + (rowb + 64 + fg*8)*2) = lo8;
    ss += __shfl_xor(ss, 1); ss += __shfl_xor(ss, 2); ss += __shfl_xor(ss, 4);
    if (fg == 0) hsq[((size_t)(c*G_ + g))*L_ + l] = ss;
  }
}

// ---------------------------------------------------------------------------
// K2: pi = softmax_k(q @ M[h]). (unchanged)
// ---------------------------------------------------------------------------
__global__ __launch_bounds__(256) void k_pi(
    const float* __restrict__ q, const float* __restrict__ M,
    float* __restrict__ pi_t) {
  __shared__ float Ms[384];
  const int g = blockIdx.x >> 2, lch = blockIdx.x & 3;
  const int n = g >> 3, h = g & 7;
  const int t = threadIdx.x;
  const int l = lch*256 + t;
  for (int u = t; u < 384; u += 256) Ms[u] = M[h*384 + u];  // M[h][e][k]
  __syncthreads();
  const float* qrow = q + (((size_t)(n*L_ + l))*H_ + h)*E_;
  float p[6] = {0.f, 0.f, 0.f, 0.f, 0.f, 0.f};
  #pragma unroll 8
  for (int e = 0; e < 64; e++) {
    float qv = qrow[e];
    #pragma unroll
    for (int k = 0; k < 6; k++) p[k] = fmaf(qv, Ms[e*6 + k], p[k]);
  }
  float mx = p[0];
  #pragma unroll
  for (int k = 1; k < 6; k++) mx = fmaxf(mx, p[k]);
  float den = 0.f;
  #pragma unroll
  for (int k = 0; k < 6; k++) den += __expf(p[k] - mx);
  float rden = __builtin_amdgcn_rcpf(den);
  #pragma unroll
  for (int k = 0; k < 6; k++)
    pi_t[((size_t)(k*G_ + g))*L_ + l] = __expf(p[k] - mx) * rden;
}

// ---------------------------------------------------------------------------
// K3: key split hi/lo + ksq. (unchanged)
// ---------------------------------------------------------------------------
__global__ __launch_bounds__(256) void k_key(
    const float* __restrict__ key, __hip_bfloat16* __restrict__ Khat,
    float* __restrict__ ksq) {
  int t = threadIdx.x; int wv = t >> 6; int lane = t & 63;
  int r = blockIdx.x*4 + wv;
  int g = r >> 10; int s = r & 1023; int n = g >> 3; int h = g & 7;
  float v = key[(((size_t)(n*S_ + s))*H_ + h)*E_ + lane];
  __hip_bfloat16 hi = __float2bfloat16(v);
  __hip_bfloat16 lo = __float2bfloat16(v - __bfloat162float(hi));
  size_t base = ((size_t)g*S_ + s)*128;
  Khat[base + lane]      = hi;
  Khat[base + 64 + lane] = lo;
  float sq = v*v;
  #pragma unroll
  for (int off = 32; off; off >>= 1) sq += __shfl_xor(sq, off);
  if (lane == 0) ksq[(size_t)g*S_ + s] = sq;
}

// ---------------------------------------------------------------------------
// K4: fused stats+emit — R12: TRANSPOSED MFMA (d[s][l] = K x H).
// Model from R10/R11 counters: occupancy is register-wall-bound at 2
// waves/SIMD (pool ~256/slot; 128 VGPR is the ceiling — 108/120/128 all gave
// ~20%). The old orientation re-read 24 tile-INVARIANT ds_read_b128 per tile
// (~50-60us of per-CU LDS pipe). Swapping MFMA operands (A=K frag, B=htilde
// frag; identical lane mappings, so the swap is free) makes each lane own ONE
// l (=lc): Zc/consts/ac collapse 28->7/16->4/24->7 regs, freeing ~50 regs to
// hold the HI halves of all 6 codes' htilde in registers (48 regs). Only the
// lo halves (2 of 6 MFMAs each) stay in LDS: 24 -> 12 ds_reads/tile. Bonus:
// mask/ksq/klen become float4 loads, out one dwordx4/lane, 16-lane butterfly
// becomes 2 shfl_xor. Arithmetic per element unchanged (reduction order only).
// K-fragments keep the R11 2-deep global prefetch (L2-resident).
// ---------------------------------------------------------------------------
#define LDS_A6LO  0                      // 96 rows * 144 B = 13824 (lo halves)
#define LDS_ZRED  13824                  // 4*96 f = 1536
#define LDS_MRED  15360                  // 4*96 f = 1536
#define LDS_CST   16896                  // 96 float2 = 768
#define LDS_TOTAL 17664

__global__ __launch_bounds__(256, 2) void k_main(
    const __hip_bfloat16* __restrict__ Ahat, const __hip_bfloat16* __restrict__ Khat,
    const float* __restrict__ hsq, const float* __restrict__ ksq,
    const float* __restrict__ mask, const float* __restrict__ klen,
    const float* __restrict__ pi_t, float* __restrict__ out) {
  extern __shared__ char smraw[];
  char*   A6     = smraw + LDS_A6LO;
  float*  zred   = (float*)(smraw + LDS_ZRED);
  float*  mred   = (float*)(smraw + LDS_MRED);
  float2* cst    = (float2*)(smraw + LDS_CST);

  const int l0 = blockIdx.x * 16; const int g = blockIdx.y; const int n = g >> 3;
  const int t = threadIdx.x; const int w = t >> 6; const int lane = t & 63;
  const int quad = lane >> 4; const int lc = lane & 15;

  // ---- stage A6 lo-halves once: 96 rows x 128B payload, stride 144 ----
  #pragma unroll
  for (int rep = 0; rep < 3; rep++) {
    int u = t + rep*256; int row = u >> 3, seg = u & 7;   // row 0..95
    int cc = row >> 4, lr = row & 15;
    *(int4*)(A6 + row*144 + seg*16) =
      *(const int4*)((const char*)Ahat +
          (((size_t)(cc*G_ + g))*L_ + l0 + lr)*256 + 128 + seg*16);
  }

  // ---- htilde HI fragments in registers: 6 codes x 2 chunks (48 VGPR) ----
  // lane (quad,lc) holds B[col = l0+lc][k-chunk quad] for hi k0-31 / k32-63.
  short8 ah[6][2];
  #pragma unroll
  for (int cc = 0; cc < 6; cc++) {
    const char* arow = (const char*)Ahat + (((size_t)(cc*G_ + g))*L_ + l0 + lc)*256;
    ah[cc][0] = *(const short8*)(arow + quad*16);
    ah[cc][1] = *(const short8*)(arow + 64 + quad*16);
  }

  // per-lane constants (one l = l0+lc per lane)
  float h1p = 1.0f  + hsq[((size_t)(1*G_ + g))*L_ + l0 + lc];
  float nh2 = 64.0f - hsq[((size_t)(2*G_ + g))*L_ + l0 + lc];   // P: +64 shift
  float h4h = -0.5f * hsq[((size_t)(4*G_ + g))*L_ + l0 + lc];
  float nh5 = -hsq[((size_t)(5*G_ + g))*L_ + l0 + lc];

  __syncthreads();                       // A6 lo staged

  // K-fragment loader (A operand; 4 x 16B from global, L2-resident)
  auto LOADK = [&](int st, short8 (&bf)[4]) {
    const char* base = (const char*)Khat +
        (((size_t)g)*S_ + st*64 + w*16 + lc)*256 + quad*16;
    #pragma unroll
    for (int kt = 0; kt < 4; kt++)
      bf[kt] = *(const short8*)(base + kt*64);
  };

  // Flat Z: Zc0..3={L,O,R,W}, zp=P(shifted). Online: (m3,z3)=Y. All lane-scalar.
  float Zc0 = 0.f, Zc1 = 0.f, Zc2 = 0.f, Zc3 = 0.f, zp = 0.f;
  float m3 = -INFINITY, z3 = 0.f;

  // ================= sweep 1: Z =================
  auto SWEEP1 = [&](int st, const short8 (&bf)[4]) {
    int sb = st*64 + w*16 + quad*4;      // lane's 4 consecutive s
    float4 mk4 = *(const float4*)(mask + ((size_t)(n*L_ + l0 + lc))*S_ + sb);
    float4 kl4 = *(const float4*)(klen + (size_t)n*S_ + sb);
    float4 kq4 = *(const float4*)(ksq  + (size_t)g*S_ + sb);
    float kq[4] = {kq4.x, kq4.y, kq4.z, kq4.w};
    float mv[4], Ev[4];
    mv[0] = mk4.x + kl4.x; mv[1] = mk4.y + kl4.y;
    mv[2] = mk4.z + kl4.z; mv[3] = mk4.w + kl4.w;
    #pragma unroll
    for (int i = 0; i < 4; i++) Ev[i] = __expf(mv[i]);
    #pragma unroll
    for (int c = 0; c < 6; c++) {
      short8 al0 = *(const short8*)(A6 + (c*16 + lc)*144 + quad*16);
      short8 al1 = *(const short8*)(A6 + (c*16 + lc)*144 + 64 + quad*16);
      floatx4 a = {0.f, 0.f, 0.f, 0.f};
      a = MFMA16(bf[0], ah[c][0], a, 0,0,0);   // Khi x Hhi (k0-31)
      a = MFMA16(bf[1], ah[c][1], a, 0,0,0);   // Khi x Hhi (k32-63)
      a = MFMA16(bf[0], al0,      a, 0,0,0);   // Khi x Hlo
      a = MFMA16(bf[1], al1,      a, 0,0,0);
      a = MFMA16(bf[2], ah[c][0], a, 0,0,0);   // Klo x Hhi
      a = MFMA16(bf[3], ah[c][1], a, 0,0,0);
      #pragma unroll
      for (int i = 0; i < 4; i++) {
        float d = a[i];
        if (c == 0) {
          Zc0 = fmaf(Ev[i], __expf(d), Zc0);
        } else if (c == 1) {
          Zc1 = fmaf(Ev[i], __builtin_amdgcn_rcpf(fmaf(-2.f, d, h1p + kq[i])), Zc1);
        } else if (c == 2) {                              // P flat, shifted
          zp += __expf(fmaf(2.f, d, nh2 - kq[i] + mv[i]));
        } else if (c == 3) {                              // Y online
          float tt = d + 1.f;
          float x  = fmaf(tt, tt, mv[i]);
          float mn = fmaxf(m3, x);
          float e  = __expf(fminf(m3, x) - mn);
          z3 = (x > m3) ? fmaf(z3, e, 1.0f) : (z3 + e);
          m3 = mn;
        } else if (c == 4) {
          Zc2 = fmaf(Ev[i], __expf(__expf(d + fmaf(-0.5f, kq[i], h4h))), Zc2);
        } else {
          float a5 = fmaf(2.f, d, nh5 - kq[i]);
          Zc3 = fmaf(Ev[i], __expf(__cosf(a5) * __expf(a5)), Zc3);
        }
      }
    }
  };

  {
    short8 bA[4], bB[4];
    LOADK(0, bA);
    #pragma unroll 1
    for (int st = 0; st < 16; st += 2) {
      LOADK(st + 1, bB);
      SWEEP1(st, bA);
      LOADK((st + 2) & 15, bA);
      SWEEP1(st + 1, bB);
    }
  }

  // ---- fold across quads (lanes lc, lc+16, lc+32, lc+48) ----
  #pragma unroll
  for (int off = 16; off < 64; off <<= 1) {
    Zc0 += __shfl_xor(Zc0, off); Zc1 += __shfl_xor(Zc1, off);
    Zc2 += __shfl_xor(Zc2, off); Zc3 += __shfl_xor(Zc3, off);
    zp  += __shfl_xor(zp,  off);
    float mo = __shfl_xor(m3, off);
    float zo = __shfl_xor(z3, off);
    float mn = fmaxf(m3, mo);
    float e  = __expf(fminf(m3, mo) - mn);
    z3 = (mo > m3) ? fmaf(z3, e, zo) : fmaf(zo, e, z3);
    m3 = mn;
  }
  if (lane < 16) {                       // quad 0 holds wave totals per l=lc
    zred[w*96 + 0*16 + lc] = Zc0; mred[w*96 + 0*16 + lc] = 0.f;
    zred[w*96 + 1*16 + lc] = Zc1; mred[w*96 + 1*16 + lc] = 0.f;
    zred[w*96 + 2*16 + lc] = zp;  mred[w*96 + 2*16 + lc] = 0.f;
    zred[w*96 + 3*16 + lc] = z3;  mred[w*96 + 3*16 + lc] = m3;
    zred[w*96 + 4*16 + lc] = Zc2; mred[w*96 + 4*16 + lc] = 0.f;
    zred[w*96 + 5*16 + lc] = Zc3; mred[w*96 + 5*16 + lc] = 0.f;
  }
  __syncthreads();
  if (t < 96) {
    int c = t >> 4;
    float z = zred[t], m = mred[t];
    if (c == 3) {
      #pragma unroll
      for (int w2 = 1; w2 < 4; w2++) {
        float mo = mred[w2*96 + t], zo = zred[w2*96 + t];
        float mn = fmaxf(m, mo);
        float e  = __expf(fminf(m, mo) - mn);
        z = (mo > m) ? fmaf(z, e, zo) : fmaf(zo, e, z);
        m = mn;
      }
    } else {
      #pragma unroll
      for (int w2 = 1; w2 < 4; w2++) z += zred[w2*96 + t];
    }
    float piv = pi_t[((size_t)((t >> 4)*G_ + g))*L_ + l0 + (t & 15)];
    cst[t] = make_float2(piv / z, m);
  }
  __syncthreads();

  float ac0 = cst[0*16 + lc].x, ac1 = cst[1*16 + lc].x, ac2 = cst[2*16 + lc].x;
  float ac3 = cst[3*16 + lc].x, ac4 = cst[4*16 + lc].x, ac5 = cst[5*16 + lc].x;
  float m3f = cst[3*16 + lc].y;

  // ================= sweep 2: emit =================
  auto SWEEP2 = [&](int st, const short8 (&bf)[4]) {
    int sb = st*64 + w*16 + quad*4;
    float4 mk4 = *(const float4*)(mask + ((size_t)(n*L_ + l0 + lc))*S_ + sb);
    float4 kl4 = *(const float4*)(klen + (size_t)n*S_ + sb);
    float4 kq4 = *(const float4*)(ksq  + (size_t)g*S_ + sb);
    float kq[4] = {kq4.x, kq4.y, kq4.z, kq4.w};
    float mv[4], Ev[4];
    mv[0] = mk4.x + kl4.x; mv[1] = mk4.y + kl4.y;
    mv[2] = mk4.z + kl4.z; mv[3] = mk4.w + kl4.w;
    #pragma unroll
    for (int i = 0; i < 4; i++) Ev[i] = __expf(mv[i]);
    float Sacc[4] = {0.f, 0.f, 0.f, 0.f};   // Ev-scaled flat codes (L,O,R,W)
    float Gg[4]   = {0.f, 0.f, 0.f, 0.f};   // P (mv folded) + Y
    #pragma unroll
    for (int c = 0; c < 6; c++) {
      short8 al0 = *(const short8*)(A6 + (c*16 + lc)*144 + quad*16);
      short8 al1 = *(const short8*)(A6 + (c*16 + lc)*144 + 64 + quad*16);
      floatx4 a = {0.f, 0.f, 0.f, 0.f};
      a = MFMA16(bf[0], ah[c][0], a, 0,0,0);
      a = MFMA16(bf[1], ah[c][1], a, 0,0,0);
      a = MFMA16(bf[0], al0,      a, 0,0,0);
      a = MFMA16(bf[1], al1,      a, 0,0,0);
      a = MFMA16(bf[2], ah[c][0], a, 0,0,0);
      a = MFMA16(bf[3], ah[c][1], a, 0,0,0);
      #pragma unroll
      for (int i = 0; i < 4; i++) {
        float d = a[i];
        if (c == 0) {
          Sacc[i] = fmaf(ac0, __expf(d), Sacc[i]);
        } else if (c == 1) {
          Sacc[i] = fmaf(ac1, __builtin_amdgcn_rcpf(fmaf(-2.f, d, h1p + kq[i])), Sacc[i]);
        } else if (c == 2) {
          Gg[i] = fmaf(ac2, __expf(fmaf(2.f, d, nh2 - kq[i] + mv[i])), Gg[i]);
        } else if (c == 3) {
          float tt = d + 1.f;
          float x  = fmaf(tt, tt, mv[i]);
          Gg[i] = fmaf(ac3, __expf(x - m3f), Gg[i]);
        } else if (c == 4) {
          Sacc[i] = fmaf(ac4, __expf(__expf(d + fmaf(-0.5f, kq[i], h4h))), Sacc[i]);
        } else {
          float a5 = fmaf(2.f, d, nh5 - kq[i]);
          Sacc[i] = fmaf(ac5, __expf(__cosf(a5) * __expf(a5)), Sacc[i]);
        }
      }
    }
    float4 ov;
    ov.x = fmaf(Ev[0], Sacc[0], Gg[0]);
    ov.y = fmaf(Ev[1], Sacc[1], Gg[1]);
    ov.z = fmaf(Ev[2], Sacc[2], Gg[2]);
    ov.w = fmaf(Ev[3], Sacc[3], Gg[3]);
    *(float4*)(out + (((size_t)g)*L_ + l0 + lc)*S_ + sb) = ov;
  };

  {
    short8 bA[4], bB[4];
    LOADK(0, bA);
    #pragma unroll 1
    for (int st = 0; st < 16; st += 2) {
      LOADK(st + 1, bB);
      SWEEP2(st, bA);
      LOADK((st + 2) & 15, bA);
      SWEEP2(st + 1, bB);
    }
  }
}

// ---------------------------------------------------------------------------
extern "C" void kernel_launch(void* const* d_in, const int* in_sizes, int n_in,
                              void* d_out, int out_size, void* d_ws, size_t ws_size,
                              hipStream_t stream) {
  (void)in_sizes; (void)n_in; (void)out_size; (void)ws_size;
  const float* q    = (const float*)d_in[0];
  const float* key  = (const float*)d_in[1];
  const float* mask = (const float*)d_in[2];
  const float* klen = (const float*)d_in[3];
  const float* M    = (const float*)d_in[4];
  const float* C    = (const float*)d_in[5];
  char* ws = (char*)d_ws;
  __hip_bfloat16* Ahat = (__hip_bfloat16*)(ws + AHAT_OFF);
  __hip_bfloat16* Khat = (__hip_bfloat16*)(ws + KHAT_OFF);
  float* pi_t    = (float*)(ws + PI_OFF);
  float* hsq     = (float*)(ws + HSQ_OFF);
  float* ksq     = (float*)(ws + KSQ_OFF);
  float* out = (float*)d_out;

  k_htilde<<<dim3(8, 6, 16), 256, 52224, stream>>>(q, C, Ahat, hsq);
  k_key<<<4096, 256, 0, stream>>>(key, Khat, ksq);
  k_pi<<<64, 256, 0, stream>>>(q, M, pi_t);
  k_main<<<dim3(64, 16), 256, LDS_TOTAL, stream>>>(Ahat, Khat, hsq, ksq, mask, klen,
                                                   pi_t, out);
}